// Round 1
// baseline (66.960 us; speedup 1.0000x reference)
//
#include <hip/hip_runtime.h>
#include <stdint.h>

#define NB   16
#define CIN  32
#define COUT 32
#define HH   256
#define WW   256
#define HWSZ (HH * WW)
#define EPSV 1e-5f

// ---------------------------------------------------------------------------
// Kernel 1: binarize + bit-pack activations.
// One uint32 per (n,h,w): bit c = (x[n,c,h,w] < 0)  (encodes -1; 0/positive -> +1).
// Each thread produces 4 consecutive packed words via float4 loads (coalesced).
// ---------------------------------------------------------------------------
__global__ __launch_bounds__(256) void pack_x_kernel(const float* __restrict__ x,
                                                     uint32_t* __restrict__ px) {
    const int tid = blockIdx.x * 256 + threadIdx.x;   // 0 .. NB*HWSZ/4 - 1
    const int wi  = tid << 2;                          // packed-word index
    const int n   = wi >> 16;                          // / HWSZ
    const int rem = wi & (HWSZ - 1);                   // h*WW + w
    const float* xp = x + (size_t)n * (CIN * HWSZ) + rem;
    uint32_t b0 = 0, b1 = 0, b2 = 0, b3 = 0;
#pragma unroll
    for (int c = 0; c < CIN; ++c) {
        const float4 v = *reinterpret_cast<const float4*>(xp + c * HWSZ);
        b0 |= (v.x < 0.f) ? (1u << c) : 0u;
        b1 |= (v.y < 0.f) ? (1u << c) : 0u;
        b2 |= (v.z < 0.f) ? (1u << c) : 0u;
        b3 |= (v.w < 0.f) ? (1u << c) : 0u;
    }
    *reinterpret_cast<uint4*>(px + wi) = make_uint4(b0, b1, b2, b3);
}

// ---------------------------------------------------------------------------
// Kernel 2: binarize + bit-pack weights.
// pw[o*9 + t] (t = kh*3+kw): bit c = (w[o,c,kh,kw] < 0).
// Note wb = sign(sign(w)+0.01): -1 iff w<0, +1 otherwise (zeros -> +1).
// ---------------------------------------------------------------------------
__global__ void pack_w_kernel(const float* __restrict__ wt,
                              uint32_t* __restrict__ pw) {
    const int j = threadIdx.x;
    if (j < COUT * 9) {
        const int o = j / 9, t = j % 9;
        uint32_t bits = 0;
#pragma unroll
        for (int c = 0; c < CIN; ++c) {
            const float v = wt[(o * CIN + c) * 9 + t];
            bits |= (v < 0.f) ? (1u << c) : 0u;
        }
        pw[j] = bits;
    }
}

// ---------------------------------------------------------------------------
// Kernel 3: XNOR-popcount conv + BN + ReLU.
// One block per (h, n) row; 256 threads = one per w. Full-row LDS tile of the
// 3 packed input rows (+1 col pad each side). Weights staged in LDS padded to
// 12 words per filter so they can be read as aligned uint4 broadcasts.
// Per output: sum = nv*32 - 2 * sum_taps popc((px ^ pw) & validmask).
// ---------------------------------------------------------------------------
__global__ __launch_bounds__(256) void biconv_main(
    const uint32_t* __restrict__ px, const uint32_t* __restrict__ pw,
    const float* __restrict__ gamma, const float* __restrict__ beta,
    const float* __restrict__ rmean, const float* __restrict__ rvar,
    float* __restrict__ out) {
    const int w = threadIdx.x;     // 0..255
    const int h = blockIdx.x;      // 0..255
    const int n = blockIdx.y;      // 0..15

    __shared__ uint4    wsh4[COUT * 3];      // 12 words per o (9 used)
    __shared__ float    sc[COUT], bi[COUT];
    __shared__ uint32_t tile[3][WW + 2];

    // stage weights (padded layout)
    uint32_t* wshw = reinterpret_cast<uint32_t*>(wsh4);
    for (int i = w; i < COUT * 12; i += 256) {
        const int o = i / 12, t = i % 12;
        wshw[i] = (t < 9) ? pw[o * 9 + t] : 0u;
    }
    // stage BN constants
    if (w < COUT) {
        const float inv = gamma[w] * rsqrtf(rvar[w] + EPSV);
        sc[w] = inv;
        bi[w] = beta[w] - rmean[w] * inv;
    }
    // stage 3 packed input rows with column padding
    const uint32_t* pxn = px + n * HWSZ;
#pragma unroll
    for (int r = 0; r < 3; ++r) {
        const int hr = h + r - 1;
        tile[r][w + 1] = (hr >= 0 && hr < HH) ? pxn[hr * WW + w] : 0u;
    }
    if (w == 0) {
#pragma unroll
        for (int r = 0; r < 3; ++r) { tile[r][0] = 0u; tile[r][WW + 1] = 0u; }
    }
    __syncthreads();

    // load the 9 neighborhood words + validity masks
    uint32_t p[9], m[9];
    const bool rv[3] = { h > 0, true, h < HH - 1 };
    const bool cv[3] = { w > 0, true, w < WW - 1 };
    int nv = 0;
#pragma unroll
    for (int dh = 0; dh < 3; ++dh) {
#pragma unroll
        for (int dw = 0; dw < 3; ++dw) {
            const int t = dh * 3 + dw;
            p[t] = tile[dh][w + dw];
            const bool v = rv[dh] && cv[dw];
            m[t] = v ? 0xffffffffu : 0u;
            nv += v ? 1 : 0;
        }
    }
    const float base = (float)(nv * 32);

    float* outp = out + (size_t)n * (COUT * HWSZ) + h * WW + w;
#pragma unroll
    for (int o = 0; o < COUT; ++o) {
        const uint4 wa = wsh4[o * 3 + 0];
        const uint4 wb = wsh4[o * 3 + 1];
        const uint4 wc = wsh4[o * 3 + 2];
        int acc = 0;
        acc += __popc((p[0] ^ wa.x) & m[0]);
        acc += __popc((p[1] ^ wa.y) & m[1]);
        acc += __popc((p[2] ^ wa.z) & m[2]);
        acc += __popc((p[3] ^ wa.w) & m[3]);
        acc += __popc((p[4] ^ wb.x) & m[4]);
        acc += __popc((p[5] ^ wb.y) & m[5]);
        acc += __popc((p[6] ^ wb.z) & m[6]);
        acc += __popc((p[7] ^ wb.w) & m[7]);
        acc += __popc((p[8] ^ wc.x) & m[8]);
        const float s = base - 2.0f * (float)acc;
        const float r = fmaf(s, sc[o], bi[o]);
        outp[o * HWSZ] = r > 0.f ? r : 0.f;
    }
}

// ---------------------------------------------------------------------------
extern "C" void kernel_launch(void* const* d_in, const int* in_sizes, int n_in,
                              void* d_out, int out_size, void* d_ws, size_t ws_size,
                              hipStream_t stream) {
    const float* x     = (const float*)d_in[0];
    const float* wt    = (const float*)d_in[1];
    const float* gamma = (const float*)d_in[2];
    const float* beta  = (const float*)d_in[3];
    const float* rmean = (const float*)d_in[4];
    const float* rvar  = (const float*)d_in[5];
    float* out = (float*)d_out;

    uint32_t* px = (uint32_t*)d_ws;                  // NB*HWSZ words = 4 MB
    uint32_t* pw = px + (size_t)NB * HWSZ;           // 288 words

    // 1) pack activations: NB*HWSZ/4 threads
    pack_x_kernel<<<dim3(NB * HWSZ / 4 / 256), dim3(256), 0, stream>>>(x, px);
    // 2) pack weights
    pack_w_kernel<<<dim3(1), dim3(288), 0, stream>>>(wt, pw);
    // 3) conv + BN + ReLU
    biconv_main<<<dim3(HH, NB), dim3(256), 0, stream>>>(px, pw, gamma, beta,
                                                        rmean, rvar, out);
}

// Round 2
// 53.616 us; speedup vs baseline: 1.2489x; 1.2489x over previous
//
#include <hip/hip_runtime.h>
#include <stdint.h>

#define NB   16
#define CIN  32
#define COUT 32
#define HH   256
#define WW   256
#define HWSZ (HH * WW)
#define EPSV 1e-5f

// ---------------------------------------------------------------------------
// Kernel 1: binarize + bit-pack weights (tiny, 1 block).
// pw[o*9 + t] (t = kh*3+kw): bit c = (w[o,c,kh,kw] < 0).
// wb = sign(sign(w)+0.01): -1 iff w<0, +1 otherwise (zeros -> +1).
// ---------------------------------------------------------------------------
__global__ void pack_w_kernel(const float* __restrict__ wt,
                              uint32_t* __restrict__ pw) {
    const int j = threadIdx.x;
    if (j < COUT * 9) {
        const int o = j / 9, t = j % 9;
        uint32_t bits = 0;
#pragma unroll
        for (int c = 0; c < CIN; ++c) {
            const float v = wt[(o * CIN + c) * 9 + t];
            bits |= (v < 0.f) ? (1u << c) : 0u;
        }
        pw[j] = bits;
    }
}

// ---------------------------------------------------------------------------
// Kernel 2 (fused): read x directly, binarize+pack 3 rows into LDS, then
// XNOR-popcount conv + BN + ReLU.
//   - XCD-chunked swizzle: consecutive blocks on one XCD process consecutive
//     h in the same n, so the 3x re-read of x rows hits the per-XCD L2.
//   - Non-temporal stores keep the write stream from evicting hot x rows.
// One block per (n,h) row; 256 threads.
// Waves 0..2 (tid<192): pack — thread (r, q) packs row r, w = 4q..4q+3 via
// float4 loads over 32 channels. Wave 3 (tid>=192): stage weights (padded to
// 12 words/filter for uint4 broadcast), BN constants, column pads.
// ---------------------------------------------------------------------------
__global__ __launch_bounds__(256) void biconv_fused(
    const float* __restrict__ x, const uint32_t* __restrict__ pw,
    const float* __restrict__ gamma, const float* __restrict__ beta,
    const float* __restrict__ rmean, const float* __restrict__ rvar,
    float* __restrict__ out) {
    // bijective XCD-chunked swizzle: 4096 blocks, 8 XCDs, 512 per XCD
    const uint32_t bid = blockIdx.x;
    const uint32_t wg  = ((bid & 7u) << 9) | (bid >> 3);
    const int n = wg >> 8;     // 0..15
    const int h = wg & 255;    // 0..255
    const int tid = threadIdx.x;

    __shared__ uint4    wsh4[COUT * 3];      // 12 words per o (9 used)
    __shared__ float    sc[COUT], bi[COUT];
    __shared__ uint32_t tile[3][WW + 2];

    if (tid < 192) {
        // ---- pack 3 input rows ----
        const int r  = tid >> 6;          // 0..2
        const int q  = tid & 63;          // quad index: w = 4q..4q+3
        const int hr = h + r - 1;
        uint32_t b0 = 0, b1 = 0, b2 = 0, b3 = 0;
        if (hr >= 0 && hr < HH) {
            const float* xp = x + (size_t)n * (CIN * HWSZ) + hr * WW + (q << 2);
#pragma unroll
            for (int c = 0; c < CIN; ++c) {
                const float4 v = *reinterpret_cast<const float4*>(xp + c * HWSZ);
                b0 |= (v.x < 0.f) ? (1u << c) : 0u;
                b1 |= (v.y < 0.f) ? (1u << c) : 0u;
                b2 |= (v.z < 0.f) ? (1u << c) : 0u;
                b3 |= (v.w < 0.f) ? (1u << c) : 0u;
            }
        }
        const int wbase = (q << 2) + 1;
        tile[r][wbase + 0] = b0;
        tile[r][wbase + 1] = b1;
        tile[r][wbase + 2] = b2;
        tile[r][wbase + 3] = b3;
    } else {
        // ---- stage weights / BN constants / pads ----
        const int t2 = tid - 192;         // 0..63
        uint32_t* wshw = reinterpret_cast<uint32_t*>(wsh4);
#pragma unroll
        for (int k = 0; k < 6; ++k) {
            const int i = t2 + 64 * k;    // 0..383
            const int o = i / 12, t = i % 12;
            wshw[i] = (t < 9) ? pw[o * 9 + t] : 0u;
        }
        if (t2 < COUT) {
            const float inv = gamma[t2] * rsqrtf(rvar[t2] + EPSV);
            sc[t2] = inv;
            bi[t2] = beta[t2] - rmean[t2] * inv;
        }
        if (t2 >= 32 && t2 < 35) {
            const int r = t2 - 32;
            tile[r][0] = 0u;
            tile[r][WW + 1] = 0u;
        }
    }
    __syncthreads();

    // ---- conv: one output column per thread ----
    const int w = tid;
    uint32_t p[9], m[9];
    const bool rv[3] = { h > 0, true, h < HH - 1 };
    const bool cv[3] = { w > 0, true, w < WW - 1 };
    int nv = 0;
#pragma unroll
    for (int dh = 0; dh < 3; ++dh) {
#pragma unroll
        for (int dw = 0; dw < 3; ++dw) {
            const int t = dh * 3 + dw;
            p[t] = tile[dh][w + dw];
            const bool v = rv[dh] && cv[dw];
            m[t] = v ? 0xffffffffu : 0u;
            nv += v ? 1 : 0;
        }
    }
    const float base = (float)(nv * 32);

    float* outp = out + (size_t)n * (COUT * HWSZ) + h * WW + w;
#pragma unroll
    for (int o = 0; o < COUT; ++o) {
        const uint4 wa = wsh4[o * 3 + 0];
        const uint4 wb = wsh4[o * 3 + 1];
        const uint4 wc = wsh4[o * 3 + 2];
        int acc = 0;
        acc += __popc((p[0] ^ wa.x) & m[0]);
        acc += __popc((p[1] ^ wa.y) & m[1]);
        acc += __popc((p[2] ^ wa.z) & m[2]);
        acc += __popc((p[3] ^ wa.w) & m[3]);
        acc += __popc((p[4] ^ wb.x) & m[4]);
        acc += __popc((p[5] ^ wb.y) & m[5]);
        acc += __popc((p[6] ^ wb.z) & m[6]);
        acc += __popc((p[7] ^ wb.w) & m[7]);
        acc += __popc((p[8] ^ wc.x) & m[8]);
        const float s = base - 2.0f * (float)acc;
        const float r = fmaf(s, sc[o], bi[o]);
        __builtin_nontemporal_store(r > 0.f ? r : 0.f, outp + o * HWSZ);
    }
}

// ---------------------------------------------------------------------------
extern "C" void kernel_launch(void* const* d_in, const int* in_sizes, int n_in,
                              void* d_out, int out_size, void* d_ws, size_t ws_size,
                              hipStream_t stream) {
    const float* x     = (const float*)d_in[0];
    const float* wt    = (const float*)d_in[1];
    const float* gamma = (const float*)d_in[2];
    const float* beta  = (const float*)d_in[3];
    const float* rmean = (const float*)d_in[4];
    const float* rvar  = (const float*)d_in[5];
    float* out = (float*)d_out;

    uint32_t* pw = (uint32_t*)d_ws;   // 288 words

    pack_w_kernel<<<dim3(1), dim3(288), 0, stream>>>(wt, pw);
    biconv_fused<<<dim3(NB * HH), dim3(256), 0, stream>>>(x, pw, gamma, beta,
                                                          rmean, rvar, out);
}